// Round 7
// baseline (285.410 us; speedup 1.0000x reference)
//
#include <hip/hip_runtime.h>
#include <stdint.h>

// DenseCaps EM routing v5: B=32, I=2048, O=64, D=16, 3 EM iterations.
// lane <-> o. 2048 blocks (b x 64 chunks), 4 waves/block x 8 i each, direct
// coalesced w_t reads. NO LDS (100%-occupancy target at 64 VGPRs): per-wave
// partial sums accumulate via coalesced global atomicAdd into L2-resident
// red[b][33][64], zeroed by hipMemsetAsync before each pass. All-VALU DPP
// softmax with max-shift precomputed in fin_k.
constexpr int Bn = 32, In = 2048;
constexpr float EPSF = 1e-7f;
constexpr int NC  = 64;        // i-chunks per batch
constexpr int IPB = In / NC;   // 32 i per block
constexpr int IPW = IPB / 4;   // 8 i per wave

template <int CTRL>
__device__ __forceinline__ float dpp_add(float x) {
  int y = __builtin_amdgcn_update_dpp(0, __float_as_int(x), CTRL, 0xF, 0xF, true);
  return x + __int_as_float(y);
}

__device__ __forceinline__ float wave_sum64(float x) {
  // rotate-reduce within 16-lane rows (all VALU, DPP), then cross-row swaps
  x = dpp_add<0x121>(x);  // row_ror:1
  x = dpp_add<0x122>(x);  // row_ror:2
  x = dpp_add<0x124>(x);  // row_ror:4
  x = dpp_add<0x128>(x);  // row_ror:8
#if __has_builtin(__builtin_amdgcn_permlane16_swap)
  {
    auto pr = __builtin_amdgcn_permlane16_swap(__float_as_uint(x), __float_as_uint(x), false, false);
    x = __uint_as_float(pr[0]) + __uint_as_float(pr[1]);
  }
#else
  x += __int_as_float(__builtin_amdgcn_ds_swizzle(__float_as_int(x), 0x401F));  // xor16
#endif
#if __has_builtin(__builtin_amdgcn_permlane32_swap)
  {
    auto pr = __builtin_amdgcn_permlane32_swap(__float_as_uint(x), __float_as_uint(x), false, false);
    x = __uint_as_float(pr[0]) + __uint_as_float(pr[1]);
  }
#else
  x += __shfl_xor(x, 32);
#endif
  return x;
}

// w[o][i][16] -> w_t[i][k][o] in float4 granularity (k = row of the 4x4)
__global__ __launch_bounds__(256) void transpose_w_k(const float4* __restrict__ w,
                                                     float4* __restrict__ w_t) {
  int idx = blockIdx.x * 256 + threadIdx.x;  // input float4 index: o*8192 + i*4 + k
  int o = idx >> 13;
  int rest = idx & 8191;
  int i = rest >> 2;
  int k = rest & 3;
  w_t[(size_t)((i << 2) + k) * 64 + o] = w[idx];
}

template <int TPASS>
__global__ __launch_bounds__(256, 4) void pass_k(const float* __restrict__ poses,
                                                 const float* __restrict__ a_in,
                                                 const float* __restrict__ w_t,
                                                 const float* __restrict__ params,
                                                 float* __restrict__ red) {
  const int gid = blockIdx.x;            // 2048 blocks
  const int xcd = gid & 7;
  const int s   = gid >> 3;              // 0..255
  const int b   = s & 31;                // batch fastest within an XCD slice
  const int cc  = xcd * 8 + (s >> 5);    // chunk 0..63; each XCD owns 8 chunks of w_t
  const int tid = threadIdx.x, wv = tid >> 6, ln = tid & 63;
  const int i0 = cc * IPB + wv * IPW;

  float mu[16], hs[16], c0 = 0.f;
  if (TPASS > 0) {
    const float4* pp4 = (const float4*)(params + (size_t)(b * 64 + ln) * 36);
#pragma unroll
    for (int k = 0; k < 4; ++k) {
      float4 v = pp4[k];
      mu[4 * k] = v.x; mu[4 * k + 1] = v.y; mu[4 * k + 2] = v.z; mu[4 * k + 3] = v.w;
    }
#pragma unroll
    for (int k = 0; k < 4; ++k) {
      float4 v = pp4[4 + k];
      hs[4 * k] = v.x; hs[4 * k + 1] = v.y; hs[4 * k + 2] = v.z; hs[4 * k + 3] = v.w;
    }
    c0 = ((const float*)pp4)[32];  // log(a_out+eps) - 0.5*sum log sig2 - max_o
  }

  float rs = 0.f, S1[16], S2[16];
#pragma unroll
  for (int d = 0; d < 16; ++d) { S1[d] = 0.f; S2[d] = 0.f; }

  const float4* wt4 = (const float4*)w_t;
  const float4* po4 = (const float4*)poses;

#pragma unroll
  for (int ii = 0; ii < IPW; ++ii) {
    const int i = i0 + ii;
    // w_t[i][k][ln] -- fully coalesced (64 lanes x 16B = 1KB per instr)
    float4 w0 = wt4[(size_t)(i * 4 + 0) * 64 + ln];
    float4 w1 = wt4[(size_t)(i * 4 + 1) * 64 + ln];
    float4 w2 = wt4[(size_t)(i * 4 + 2) * 64 + ln];
    float4 w3 = wt4[(size_t)(i * 4 + 3) * 64 + ln];
    const float4* pp = po4 + ((size_t)b * In + i) * 4;  // wave-uniform
    float4 p0 = pp[0], p1 = pp[1], p2 = pp[2], p3 = pp[3];
    float V[16];
#define VROW(p, Pv)                                                              \
    V[p * 4 + 0] = fmaf(Pv.w, w3.x, fmaf(Pv.z, w2.x, fmaf(Pv.y, w1.x, Pv.x * w0.x))); \
    V[p * 4 + 1] = fmaf(Pv.w, w3.y, fmaf(Pv.z, w2.y, fmaf(Pv.y, w1.y, Pv.x * w0.y))); \
    V[p * 4 + 2] = fmaf(Pv.w, w3.z, fmaf(Pv.z, w2.z, fmaf(Pv.y, w1.z, Pv.x * w0.z))); \
    V[p * 4 + 3] = fmaf(Pv.w, w3.w, fmaf(Pv.z, w2.w, fmaf(Pv.y, w1.w, Pv.x * w0.w)));
    VROW(0, p0) VROW(1, p1) VROW(2, p2) VROW(3, p3)
#undef VROW
    const float a = a_in[(size_t)b * In + i];
    float r;
    if (TPASS == 0) {
      r = a * 0.015625f;  // R uniform at t=0
    } else {
      // 4-way split accumulator shortens the serial logit chain
      float u0 = c0, u1 = 0.f, u2 = 0.f, u3 = 0.f;
#pragma unroll
      for (int j = 0; j < 4; ++j) {
        float d0 = V[j] - mu[j];           u0 = fmaf(-d0 * d0, hs[j], u0);
        float d1 = V[4 + j] - mu[4 + j];   u1 = fmaf(-d1 * d1, hs[4 + j], u1);
        float d2 = V[8 + j] - mu[8 + j];   u2 = fmaf(-d2 * d2, hs[8 + j], u2);
        float d3 = V[12 + j] - mu[12 + j]; u3 = fmaf(-d3 * d3, hs[12 + j], u3);
      }
      float u = (u0 + u1) + (u2 + u3);
      float e = __expf(u);                 // u <= 0 by construction (max-shift)
      float ss = wave_sum64(e) + 1e-37f;
      r = a * e * __builtin_amdgcn_rcpf(ss);
    }
    rs += r;
#pragma unroll
    for (int d = 0; d < 16; ++d) {
      float t1 = r * V[d];
      S1[d] += t1;
      S2[d] = fmaf(t1, V[d], S2[d]);
    }
  }

  // epilogue: wave-wide coalesced global atomic accumulate (red pre-zeroed).
  // 64 lanes hit 64 consecutive floats -> one coalesced atomic op per row.
  float* rp = red + (size_t)b * 2112 + ln;
  atomicAdd(rp, rs);
#pragma unroll
  for (int d = 0; d < 16; ++d) {
    atomicAdd(rp + (1 + d) * 64, S1[d]);
    atomicAdd(rp + (17 + d) * 64, S2[d]);
  }
}

template <int TPASS>
__global__ __launch_bounds__(256) void fin_k(const float* __restrict__ red,
                                             const float* __restrict__ beta_a,
                                             const float* __restrict__ beta_u,
                                             float* __restrict__ params,
                                             float* __restrict__ out) {
  const int g = blockIdx.x * 256 + threadIdx.x;  // 0..Bn*On-1; wave spans one b
  const int b = g >> 6, o = g & 63;
  const float* base = red + (size_t)b * 2112 + o;
  const float r_sum = base[0] + EPSF;
  const float inv = 1.f / r_sum;
  float muv[16], sg[16], lsum = 0.f;
#pragma unroll
  for (int d = 0; d < 16; ++d) {
    float m = base[(1 + d) * 64] * inv;
    float s2 = fmaxf(base[(17 + d) * 64] * inv - m * m, 0.f) + EPSF;  // E[V^2]-mu^2
    muv[d] = m; sg[d] = s2; lsum += logf(s2);
  }
  const float cost = (16.f * beta_u[o] + 0.5f * lsum) * r_sum;
  const float aout = 1.f / (1.f + __expf(-(float)(TPASS + 1) * (beta_a[o] - cost)));
  if (TPASS < 2) {
    float c0 = logf(aout + EPSF) - 0.5f * lsum;
    float mx = c0;  // wave-wide max over o (lanes of this wave = o 0..63 of one b)
#pragma unroll
    for (int k = 1; k < 64; k <<= 1) mx = fmaxf(mx, __shfl_xor(mx, k));
    float* pp = params + (size_t)g * 36;
#pragma unroll
    for (int d = 0; d < 16; ++d) {
      pp[d] = muv[d];
      pp[16 + d] = 0.5f / sg[d];
    }
    pp[32] = c0 - mx;  // pre-shifted logit constant
  } else {
#pragma unroll
    for (int d = 0; d < 16; ++d) out[(size_t)g * 16 + d] = muv[d];
    out[Bn * 64 * 16 + g] = aout;
  }
}

extern "C" void kernel_launch(void* const* d_in, const int* in_sizes, int n_in,
                              void* d_out, int out_size, void* d_ws, size_t ws_size,
                              hipStream_t stream) {
  const float* poses  = (const float*)d_in[0];
  const float* a_in   = (const float*)d_in[1];
  const float* w      = (const float*)d_in[2];
  const float* beta_a = (const float*)d_in[3];
  const float* beta_u = (const float*)d_in[4];
  float* out = (float*)d_out;

  float* w_t    = (float*)d_ws;                 // 8 MB
  float* red    = w_t + (size_t)In * 64 * 16;   // 270 KB (L2-resident accumulator)
  float* params = red + (size_t)Bn * 33 * 64;   // 295 KB

  transpose_w_k<<<dim3(In * 64 * 4 / 256), 256, 0, stream>>>((const float4*)w, (float4*)w_t);

  const size_t red_bytes = (size_t)Bn * 33 * 64 * sizeof(float);
  dim3 pg(Bn * NC);  // 2048 blocks = 8/CU at 64 VGPR, 0 LDS -> full residency

  hipMemsetAsync(red, 0, red_bytes, stream);
  pass_k<0><<<pg, 256, 0, stream>>>(poses, a_in, w_t, params, red);
  fin_k<0><<<Bn * 64 / 256, 256, 0, stream>>>(red, beta_a, beta_u, params, out);

  hipMemsetAsync(red, 0, red_bytes, stream);
  pass_k<1><<<pg, 256, 0, stream>>>(poses, a_in, w_t, params, red);
  fin_k<1><<<Bn * 64 / 256, 256, 0, stream>>>(red, beta_a, beta_u, params, out);

  hipMemsetAsync(red, 0, red_bytes, stream);
  pass_k<2><<<pg, 256, 0, stream>>>(poses, a_in, w_t, params, red);
  fin_k<2><<<Bn * 64 / 256, 256, 0, stream>>>(red, beta_a, beta_u, params, out);
}

// Round 8
// 161.206 us; speedup vs baseline: 1.7705x; 1.7705x over previous
//
#include <hip/hip_runtime.h>
#include <stdint.h>

// DenseCaps EM routing v6: B=32, I=2048, O=64, D=16, 3 EM iterations.
// lane <-> o. 1024 blocks (32 b x 32 chunks = exactly 4/CU), 4 waves/block
// x 16 i each. launch_bounds(256,2) -> 128 VGPRs (no spills; v4's 64-VGPR
// alloc caused ~39MB/pass scratch traffic). Direct coalesced w_t reads,
// wave-uniform pose/a loads scalarized via readfirstlane, all-VALU DPP
// softmax with max-shift precomputed in fin_k. No atomics (v5 lesson:
// cross-XCD atomicAdd writes through to HBM, ~70MB/pass).
constexpr int Bn = 32, In = 2048;
constexpr float EPSF = 1e-7f;
constexpr int NC  = 32;        // i-chunks per batch
constexpr int IPB = In / NC;   // 64 i per block
constexpr int IPW = IPB / 4;   // 16 i per wave

template <int CTRL>
__device__ __forceinline__ float dpp_add(float x) {
  int y = __builtin_amdgcn_update_dpp(0, __float_as_int(x), CTRL, 0xF, 0xF, true);
  return x + __int_as_float(y);
}

__device__ __forceinline__ float wave_sum64(float x) {
  // rotate-reduce within 16-lane rows (all VALU, DPP), then cross-row swaps
  x = dpp_add<0x121>(x);  // row_ror:1
  x = dpp_add<0x122>(x);  // row_ror:2
  x = dpp_add<0x124>(x);  // row_ror:4
  x = dpp_add<0x128>(x);  // row_ror:8
#if __has_builtin(__builtin_amdgcn_permlane16_swap)
  {
    auto pr = __builtin_amdgcn_permlane16_swap(__float_as_uint(x), __float_as_uint(x), false, false);
    x = __uint_as_float(pr[0]) + __uint_as_float(pr[1]);
  }
#else
  x += __int_as_float(__builtin_amdgcn_ds_swizzle(__float_as_int(x), 0x401F));  // xor16
#endif
#if __has_builtin(__builtin_amdgcn_permlane32_swap)
  {
    auto pr = __builtin_amdgcn_permlane32_swap(__float_as_uint(x), __float_as_uint(x), false, false);
    x = __uint_as_float(pr[0]) + __uint_as_float(pr[1]);
  }
#else
  x += __shfl_xor(x, 32);
#endif
  return x;
}

// w[o][i][16] -> w_t[i][k][o] in float4 granularity (k = row of the 4x4)
__global__ __launch_bounds__(256) void transpose_w_k(const float4* __restrict__ w,
                                                     float4* __restrict__ w_t) {
  int idx = blockIdx.x * 256 + threadIdx.x;  // input float4 index: o*8192 + i*4 + k
  int o = idx >> 13;
  int rest = idx & 8191;
  int i = rest >> 2;
  int k = rest & 3;
  w_t[(size_t)((i << 2) + k) * 64 + o] = w[idx];
}

template <int TPASS>
__global__ __launch_bounds__(256, 2) void pass_k(const float* __restrict__ poses,
                                                 const float* __restrict__ a_in,
                                                 const float* __restrict__ w_t,
                                                 const float* __restrict__ params,
                                                 float* __restrict__ partials) {
  const int gid = blockIdx.x;            // 1024 blocks
  const int xcd = gid & 7;
  const int s   = gid >> 3;              // 0..127
  const int b   = s & 31;                // batch fastest within an XCD slice
  const int cc  = xcd * 4 + (s >> 5);    // chunk 0..31; each XCD owns 4 chunks of w_t
  const int tid = threadIdx.x, wv = tid >> 6, ln = tid & 63;
  const int i0 = __builtin_amdgcn_readfirstlane(cc * IPB + wv * IPW);  // wave-uniform

  float mu[16], hs[16], c0 = 0.f;
  if (TPASS > 0) {
    const float4* pp4 = (const float4*)(params + (size_t)(b * 64 + ln) * 36);
#pragma unroll
    for (int k = 0; k < 4; ++k) {
      float4 v = pp4[k];
      mu[4 * k] = v.x; mu[4 * k + 1] = v.y; mu[4 * k + 2] = v.z; mu[4 * k + 3] = v.w;
    }
#pragma unroll
    for (int k = 0; k < 4; ++k) {
      float4 v = pp4[4 + k];
      hs[4 * k] = v.x; hs[4 * k + 1] = v.y; hs[4 * k + 2] = v.z; hs[4 * k + 3] = v.w;
    }
    c0 = ((const float*)pp4)[32];  // log(a_out+eps) - 0.5*sum log sig2 - max_o
  }

  float rs = 0.f, S1[16], S2[16];
#pragma unroll
  for (int d = 0; d < 16; ++d) { S1[d] = 0.f; S2[d] = 0.f; }

  const float4* wt4 = (const float4*)w_t;
  const float* pbase = poses + ((size_t)b * In + i0) * 16;  // uniform -> s_load
  const float* abase = a_in + (size_t)b * In + i0;

#pragma unroll 4
  for (int ii = 0; ii < IPW; ++ii) {
    const int i = i0 + ii;
    // w_t[i][k][ln] -- fully coalesced (64 lanes x 16B = 1KB per instr)
    float4 w0 = wt4[(size_t)(i * 4 + 0) * 64 + ln];
    float4 w1 = wt4[(size_t)(i * 4 + 1) * 64 + ln];
    float4 w2 = wt4[(size_t)(i * 4 + 2) * 64 + ln];
    float4 w3 = wt4[(size_t)(i * 4 + 3) * 64 + ln];
    const float4* pp = (const float4*)(pbase + ii * 16);
    float4 p0 = pp[0], p1 = pp[1], p2 = pp[2], p3 = pp[3];
    float V[16];
#define VROW(p, Pv)                                                              \
    V[p * 4 + 0] = fmaf(Pv.w, w3.x, fmaf(Pv.z, w2.x, fmaf(Pv.y, w1.x, Pv.x * w0.x))); \
    V[p * 4 + 1] = fmaf(Pv.w, w3.y, fmaf(Pv.z, w2.y, fmaf(Pv.y, w1.y, Pv.x * w0.y))); \
    V[p * 4 + 2] = fmaf(Pv.w, w3.z, fmaf(Pv.z, w2.z, fmaf(Pv.y, w1.z, Pv.x * w0.z))); \
    V[p * 4 + 3] = fmaf(Pv.w, w3.w, fmaf(Pv.z, w2.w, fmaf(Pv.y, w1.w, Pv.x * w0.w)));
    VROW(0, p0) VROW(1, p1) VROW(2, p2) VROW(3, p3)
#undef VROW
    const float a = abase[ii];
    float r;
    if (TPASS == 0) {
      r = a * 0.015625f;  // R uniform at t=0
    } else {
      // 4-way split accumulator shortens the serial logit chain
      float u0 = c0, u1 = 0.f, u2 = 0.f, u3 = 0.f;
#pragma unroll
      for (int j = 0; j < 4; ++j) {
        float d0 = V[j] - mu[j];           u0 = fmaf(-d0 * d0, hs[j], u0);
        float d1 = V[4 + j] - mu[4 + j];   u1 = fmaf(-d1 * d1, hs[4 + j], u1);
        float d2 = V[8 + j] - mu[8 + j];   u2 = fmaf(-d2 * d2, hs[8 + j], u2);
        float d3 = V[12 + j] - mu[12 + j]; u3 = fmaf(-d3 * d3, hs[12 + j], u3);
      }
      float u = (u0 + u1) + (u2 + u3);
      float e = __expf(u);                 // u <= 0 by construction (max-shift)
      float ss = wave_sum64(e) + 1e-37f;
      r = a * e * __builtin_amdgcn_rcpf(ss);
    }
    rs += r;
#pragma unroll
    for (int d = 0; d < 16; ++d) {
      float t1 = r * V[d];
      S1[d] += t1;
      S2[d] = fmaf(t1, V[d], S2[d]);
    }
  }

  // 4-wave LDS reduce -> one partial row per (b, cc)
  __shared__ float lds[4][33][64];
  lds[wv][0][ln] = rs;
#pragma unroll
  for (int d = 0; d < 16; ++d) {
    lds[wv][1 + d][ln] = S1[d];
    lds[wv][17 + d][ln] = S2[d];
  }
  __syncthreads();
  for (int idx = tid; idx < 33 * 64; idx += 256) {
    int j = idx >> 6, o = idx & 63;
    float ssum = lds[0][j][o] + lds[1][j][o] + lds[2][j][o] + lds[3][j][o];
    partials[((size_t)(b * NC + cc) * 33 + j) * 64 + o] = ssum;
  }
}

__global__ __launch_bounds__(256) void red_k(const float* __restrict__ partials,
                                             float* __restrict__ red) {
  const int idx = blockIdx.x * 256 + threadIdx.x;  // 0 .. Bn*2112-1
  const int b = idx / 2112;
  const int rr = idx - b * 2112;
  const float* base = partials + (size_t)b * NC * 2112 + rr;
  float s = 0.f;
#pragma unroll 8
  for (int c = 0; c < NC; ++c) s += base[(size_t)c * 2112];
  red[idx] = s;
}

template <int TPASS>
__global__ __launch_bounds__(256) void fin_k(const float* __restrict__ red,
                                             const float* __restrict__ beta_a,
                                             const float* __restrict__ beta_u,
                                             float* __restrict__ params,
                                             float* __restrict__ out) {
  const int g = blockIdx.x * 256 + threadIdx.x;  // 0..Bn*On-1; wave spans one b
  const int b = g >> 6, o = g & 63;
  const float* base = red + (size_t)b * 2112 + o;
  const float r_sum = base[0] + EPSF;
  const float inv = 1.f / r_sum;
  float muv[16], sg[16], lsum = 0.f;
#pragma unroll
  for (int d = 0; d < 16; ++d) {
    float m = base[(1 + d) * 64] * inv;
    float s2 = fmaxf(base[(17 + d) * 64] * inv - m * m, 0.f) + EPSF;  // E[V^2]-mu^2
    muv[d] = m; sg[d] = s2; lsum += logf(s2);
  }
  const float cost = (16.f * beta_u[o] + 0.5f * lsum) * r_sum;
  const float aout = 1.f / (1.f + __expf(-(float)(TPASS + 1) * (beta_a[o] - cost)));
  if (TPASS < 2) {
    float c0 = logf(aout + EPSF) - 0.5f * lsum;
    float mx = c0;  // wave-wide max over o (lanes of this wave = o 0..63 of one b)
#pragma unroll
    for (int k = 1; k < 64; k <<= 1) mx = fmaxf(mx, __shfl_xor(mx, k));
    float* pp = params + (size_t)g * 36;
#pragma unroll
    for (int d = 0; d < 16; ++d) {
      pp[d] = muv[d];
      pp[16 + d] = 0.5f / sg[d];
    }
    pp[32] = c0 - mx;  // pre-shifted logit constant
  } else {
#pragma unroll
    for (int d = 0; d < 16; ++d) out[(size_t)g * 16 + d] = muv[d];
    out[Bn * 64 * 16 + g] = aout;
  }
}

extern "C" void kernel_launch(void* const* d_in, const int* in_sizes, int n_in,
                              void* d_out, int out_size, void* d_ws, size_t ws_size,
                              hipStream_t stream) {
  const float* poses  = (const float*)d_in[0];
  const float* a_in   = (const float*)d_in[1];
  const float* w      = (const float*)d_in[2];
  const float* beta_a = (const float*)d_in[3];
  const float* beta_u = (const float*)d_in[4];
  float* out = (float*)d_out;

  float* w_t      = (float*)d_ws;                          // 8 MB
  float* partials = w_t + (size_t)In * 64 * 16;            // 8.65 MB
  float* red      = partials + (size_t)Bn * NC * 33 * 64;  // 270 KB
  float* params   = red + (size_t)Bn * 33 * 64;            // 295 KB

  transpose_w_k<<<dim3(In * 64 * 4 / 256), 256, 0, stream>>>((const float4*)w, (float4*)w_t);

  dim3 pg(Bn * NC);            // 1024 blocks = exactly 4/CU (128 VGPR, 33KB LDS)
  dim3 rg(Bn * 33 * 64 / 256); // 264 blocks
  pass_k<0><<<pg, 256, 0, stream>>>(poses, a_in, w_t, params, partials);
  red_k<<<rg, 256, 0, stream>>>(partials, red);
  fin_k<0><<<Bn * 64 / 256, 256, 0, stream>>>(red, beta_a, beta_u, params, out);
  pass_k<1><<<pg, 256, 0, stream>>>(poses, a_in, w_t, params, partials);
  red_k<<<rg, 256, 0, stream>>>(partials, red);
  fin_k<1><<<Bn * 64 / 256, 256, 0, stream>>>(red, beta_a, beta_u, params, out);
  pass_k<2><<<pg, 256, 0, stream>>>(poses, a_in, w_t, params, partials);
  red_k<<<rg, 256, 0, stream>>>(partials, red);
  fin_k<2><<<Bn * 64 / 256, 256, 0, stream>>>(red, beta_a, beta_u, params, out);
}